// Round 12
// baseline (108.266 us; speedup 1.0000x reference)
//
#include <hip/hip_runtime.h>

typedef __bf16 bf16_t;
typedef bf16_t bf16x4 __attribute__((ext_vector_type(4)));
typedef bf16_t bf16x8 __attribute__((ext_vector_type(8)));
typedef float f32x4 __attribute__((ext_vector_type(4)));
typedef float f32x16 __attribute__((ext_vector_type(16)));

namespace {
constexpr int kNH  = 16;
constexpr int kHD  = 64;
constexpr int kHID = kNH * kHD;   // 1024
constexpr int kKP  = 72;          // LDS pitch (bf16): 144B rows, b128-aligned
constexpr int oQ = 0;             // Q tile 32 x kKP (shared)
constexpr int oK = 32 * kKP;      // + wave*32*kKP (per-wave private K tile)
constexpr int kOmPitch = 68;      // epilogue float pitch
// main: (32 + 4*32)*72*2 = 23040 B; epilogue: 4*32*68*4 + 256*4 = 35840 B
constexpr int kSmBytes = 35840;   // -> 4 blocks/CU (143 KB of 160)
}

// TLP is the lever this round: 1024 blocks x 4 waves at <=128 VGPR gives
// 4 waves/SIMD (vs 2). Register diet: Oa32 + vv32 (V backedge prefetch) +
// transients (va16, kbatch16, cs16/p16 sequenced) ~ 110-126 peak. K has no
// backedge register prefetch: staged in-iteration, 2 batches of 4 rows;
// its L2 latency is covered by the 4-way wave interleave.
__global__ __launch_bounds__(256, 4)
void fattn_kernel(const float* __restrict__ Qg, const float* __restrict__ Kg,
                  const float* __restrict__ Vg, float* __restrict__ Og) {
  __shared__ __align__(16) unsigned char smraw[kSmBytes];
  bf16_t* sm = (bf16_t*)smraw;

  const int bid  = blockIdx.x;
  const int head = bid & (kNH - 1);
  // 4-way complementary balance: co-resident blocks b, b+256, b+512, b+768
  // get mblk {63-i, i, 47-i, 16+i} -> per-CU work sum = 126 tiles, constant.
  // Heaviest group (g=0) dispatches first.
  const int q16  = bid >> 4;          // 0..63
  const int g    = q16 >> 4;
  const int i16  = q16 & 15;
  const int mblk = (g == 0) ? (63 - i16) : (g == 1) ? i16
                 : (g == 2) ? (47 - i16) : (16 + i16);
  const int m0   = mblk * 32;
  const int mtk  = mblk;              // last 32-key tile index

  const int tid  = threadIdx.x;
  const int wave = tid >> 6;          // key-group: tiles jt == wave (mod 4)
  const int lane = tid & 63;
  const int h    = lane >> 5;
  const int m31  = lane & 31;

  bf16_t* qs = sm + oQ;
  bf16_t* ks = sm + oK + wave * 32 * kKP;

  const float kQScale = 0.125f * 1.44269504088896340736f;  // 1/sqrt(64)*log2(e)

  // ---- stage Q tile (32 rows) cooperatively; one prologue barrier ----
  #pragma unroll
  for (int i = 0; i < 2; ++i) {
    const int idx = tid + 256 * i;          // 512 float4s
    const int row = idx >> 4;
    const int c4  = (idx & 15) * 4;
    const float4 f = *(const float4*)(Qg + (size_t)(m0 + row) * kHID + head * kHD + c4);
    bf16x4 hq;
    hq[0] = (bf16_t)(f.x * kQScale); hq[1] = (bf16_t)(f.y * kQScale);
    hq[2] = (bf16_t)(f.z * kQScale); hq[3] = (bf16_t)(f.w * kQScale);
    *(bf16x4*)(qs + row * kKP + c4) = hq;
  }
  __syncthreads();

  // O^T accumulators (32 regs) + l partial
  f32x16 Oa0, Oa1;
  #pragma unroll
  for (int r = 0; r < 16; ++r) { Oa0[r] = 0.f; Oa1[r] = 0.f; }
  float lacc = 0.f;

  const int krow0 = lane >> 4;
  const int kc4   = (lane & 15) * 4;
  const float* kbase = Kg + head * kHD + kc4;
  const float* vbase = Vg + head * kHD + (size_t)(4 * h) * kHID + m31;

  float vv[32];   // V prefetch (kappa order), spans backedge — only backedge regs

  if (wave <= mtk) {
    const float* vt0 = vbase + (size_t)(wave * 32) * kHID;
    #pragma unroll
    for (int db = 0; db < 2; ++db)
      #pragma unroll
      for (int tp = 0; tp < 2; ++tp)
        #pragma unroll
        for (int j = 0; j < 8; ++j)
          vv[db * 16 + tp * 8 + j] =
              vt0[(size_t)(16 * tp + (j & 3) + 8 * (j >> 2)) * kHID + 32 * db];
  }

  for (int jt = wave; jt <= mtk; jt += 4) {
    const int kv0 = jt * 32;

    // a) consume vv into V A-frags BEFORE the refill overwrites it (WAR by order)
    bf16x8 va0, va1, va2, va3;
    #pragma unroll
    for (int j = 0; j < 8; ++j) {
      va0[j] = (bf16_t)vv[j];
      va1[j] = (bf16_t)vv[8 + j];
      va2[j] = (bf16_t)vv[16 + j];
      va3[j] = (bf16_t)vv[24 + j];
    }

    // b) prefetch next V tile (full iteration of cover)
    if (jt + 4 <= mtk) {
      const float* vt0 = vbase + (size_t)((jt + 4) * 32) * kHID;
      #pragma unroll
      for (int db = 0; db < 2; ++db)
        #pragma unroll
        for (int tp = 0; tp < 2; ++tp)
          #pragma unroll
          for (int j = 0; j < 8; ++j)
            vv[db * 16 + tp * 8 + j] =
                vt0[(size_t)(16 * tp + (j & 3) + 8 * (j >> 2)) * kHID + 32 * db];
    }

    // c) stage THIS tile's K in two 4-row batches (16 transient regs, no backedge)
    #pragma unroll
    for (int b = 0; b < 2; ++b) {
      float4 kr[4];
      #pragma unroll
      for (int i = 0; i < 4; ++i)
        kr[i] = *(const float4*)(kbase + (size_t)(kv0 + krow0 + 4 * (4 * b + i)) * kHID);
      #pragma unroll
      for (int i = 0; i < 4; ++i) {
        bf16x4 hk;
        hk[0] = (bf16_t)kr[i].x; hk[1] = (bf16_t)kr[i].y;
        hk[2] = (bf16_t)kr[i].z; hk[3] = (bf16_t)kr[i].w;
        *(bf16x4*)(ks + (krow0 + 4 * (4 * b + i)) * kKP + kc4) = hk;
      }
    }

    // d) S^T = K * Q^T (af and qf both from LDS; same-wave DS ordering)
    f32x16 cs;
    #pragma unroll
    for (int r = 0; r < 16; ++r) cs[r] = 0.f;
    #pragma unroll
    for (int t = 0; t < 4; ++t) {
      bf16x8 af = *(const bf16x8*)(ks + m31 * kKP + 16 * t + 8 * h);
      bf16x8 qf = *(const bf16x8*)(qs + m31 * kKP + 16 * t + 8 * h);
      cs = __builtin_amdgcn_mfma_f32_32x32x16_bf16(af, qf, cs, 0, 0, 0);
    }
    // C layout: key-row kr = (r&3)+8*(r>>2)+4h, q-col = m31

    // e) fixed-reference softmax (mask only on diagonal tile)
    float p[16];
    if (jt == mtk) {
      #pragma unroll
      for (int r = 0; r < 16; ++r) {
        const int kr = (r & 3) + 8 * (r >> 2) + 4 * h;
        const float e = __builtin_amdgcn_exp2f(cs[r]);
        p[r] = (kr <= m31) ? e : 0.f;
        lacc += p[r];
      }
    } else {
      #pragma unroll
      for (int r = 0; r < 16; ++r) { p[r] = __builtin_amdgcn_exp2f(cs[r]); lacc += p[r]; }
    }

    // f) P^T B-frags straight from C-regs; PV (kappa absorbed by V load order)
    bf16x8 pb0, pb1;
    #pragma unroll
    for (int j = 0; j < 8; ++j) { pb0[j] = (bf16_t)p[j]; pb1[j] = (bf16_t)p[8 + j]; }
    Oa0 = __builtin_amdgcn_mfma_f32_32x32x16_bf16(va0, pb0, Oa0, 0, 0, 0);
    Oa1 = __builtin_amdgcn_mfma_f32_32x32x16_bf16(va2, pb0, Oa1, 0, 0, 0);
    Oa0 = __builtin_amdgcn_mfma_f32_32x32x16_bf16(va1, pb1, Oa0, 0, 0, 0);
    Oa1 = __builtin_amdgcn_mfma_f32_32x32x16_bf16(va3, pb1, Oa1, 0, 0, 0);
  }

  // ---- epilogue: 4-way additive merge via LDS (R7-verified) ----
  __syncthreads();
  float* fv   = (float*)smraw;
  float* Om   = fv + wave * 32 * kOmPitch;
  float* larr = fv + 4 * 32 * kOmPitch;

  #pragma unroll
  for (int md = 0; md < 2; ++md) {
    const f32x16& Oa = md ? Oa1 : Oa0;
    #pragma unroll
    for (int q = 0; q < 4; ++q) {
      f32x4 v;
      #pragma unroll
      for (int e = 0; e < 4; ++e) v[e] = Oa[4 * q + e];
      *(f32x4*)(Om + (size_t)m31 * kOmPitch + 32 * md + 8 * q + 4 * h) = v;
    }
  }
  larr[wave * 64 + lane] = lacc;
  __syncthreads();

  const int row = tid >> 3;
  const int c0  = (tid & 7) * 8;
  float l = 0.f;
  #pragma unroll
  for (int w = 0; w < 4; ++w)
    l += larr[w * 64 + row] + larr[w * 64 + 32 + row];
  const float inv = 1.f / l;

  f32x4 o0, o1;
  #pragma unroll
  for (int e = 0; e < 4; ++e) { o0[e] = 0.f; o1[e] = 0.f; }
  #pragma unroll
  for (int w = 0; w < 4; ++w) {
    const float* src = fv + w * 32 * kOmPitch + (size_t)row * kOmPitch + c0;
    f32x4 a = *(const f32x4*)(src);
    f32x4 b = *(const f32x4*)(src + 4);
    #pragma unroll
    for (int e = 0; e < 4; ++e) { o0[e] += a[e]; o1[e] += b[e]; }
  }
  #pragma unroll
  for (int e = 0; e < 4; ++e) { o0[e] *= inv; o1[e] *= inv; }

  float* dst = Og + (size_t)(m0 + row) * kHID + head * kHD + c0;
  *(f32x4*)(dst)     = o0;
  *(f32x4*)(dst + 4) = o1;
}

extern "C" void kernel_launch(void* const* d_in, const int* in_sizes, int n_in,
                              void* d_out, int out_size, void* d_ws, size_t ws_size,
                              hipStream_t stream) {
  (void)in_sizes; (void)n_in; (void)d_ws; (void)ws_size; (void)out_size;
  const float* Q = (const float*)d_in[0];
  const float* K = (const float*)d_in[1];
  const float* V = (const float*)d_in[2];
  float* O = (float*)d_out;
  dim3 grid(1024);   // 16 heads x 64 q-tiles (32 rows), 4-way balanced
  dim3 block(256);   // 4 waves = 4 key-groups, barrier-free main loop
  hipLaunchKernelGGL(fattn_kernel, grid, block, 0, stream, Q, K, V, O);
}

// Round 13
// 96.156 us; speedup vs baseline: 1.1259x; 1.1259x over previous
//
#include <hip/hip_runtime.h>

typedef __bf16 bf16_t;
typedef bf16_t bf16x4 __attribute__((ext_vector_type(4)));
typedef bf16_t bf16x8 __attribute__((ext_vector_type(8)));
typedef float f32x4 __attribute__((ext_vector_type(4)));
typedef float f32x16 __attribute__((ext_vector_type(16)));

namespace {
constexpr int kNH  = 16;
constexpr int kHD  = 64;
constexpr int kHID = kNH * kHD;   // 1024
constexpr int kKP  = 72;          // LDS pitch (bf16): 144B rows, b128-aligned
constexpr int oQ = 0;             // Q tile 32 x kKP (shared)
constexpr int oK = 32 * kKP;      // + wave*32*kKP (per-wave private K tile)
constexpr int kOmPitch = 68;      // epilogue float pitch
// main: (32 + 4*32)*72*2 = 23040 B; epilogue: 4*32*68*4 + 256*4 = 35840 B
constexpr int kSmBytes = 35840;   // 3 blocks/CU -> 105 KB of 160
}

// Register ledger (the lesson of R6/R9/R12: AGPRs share the unified budget):
// AGPR ~64 (Oa32 + cs16 + operand copies) + arch ~105 (vv32 + va16 + kb16 +
// p16 + pb8 + addr/misc ~17) ≈ 169 <= 170 = (256,3) cap. (256,4)=128 spilled
// (R12: 64 arch + 64 agpr, vv -> scratch, WRITE_SIZE 22 MB). (256,2)=256 fits
// but gives only 2 waves/SIMD (R11, 31 us). This round changes ONLY the bound.
__global__ __launch_bounds__(256, 3)
void fattn_kernel(const float* __restrict__ Qg, const float* __restrict__ Kg,
                  const float* __restrict__ Vg, float* __restrict__ Og) {
  __shared__ __align__(16) unsigned char smraw[kSmBytes];
  bf16_t* sm = (bf16_t*)smraw;

  const int bid  = blockIdx.x;
  const int head = bid & (kNH - 1);
  // 4-way complementary balance, heavy groups dispatch first (LPT)
  const int q16  = bid >> 4;          // 0..63
  const int g    = q16 >> 4;
  const int i16  = q16 & 15;
  const int mblk = (g == 0) ? (63 - i16) : (g == 1) ? i16
                 : (g == 2) ? (47 - i16) : (16 + i16);
  const int m0   = mblk * 32;
  const int mtk  = mblk;              // last 32-key tile index

  const int tid  = threadIdx.x;
  const int wave = tid >> 6;          // key-group: tiles jt == wave (mod 4)
  const int lane = tid & 63;
  const int h    = lane >> 5;
  const int m31  = lane & 31;

  bf16_t* qs = sm + oQ;
  bf16_t* ks = sm + oK + wave * 32 * kKP;

  const float kQScale = 0.125f * 1.44269504088896340736f;  // 1/sqrt(64)*log2(e)

  // ---- stage Q tile (32 rows) cooperatively; one prologue barrier ----
  #pragma unroll
  for (int i = 0; i < 2; ++i) {
    const int idx = tid + 256 * i;          // 512 float4s
    const int row = idx >> 4;
    const int c4  = (idx & 15) * 4;
    const float4 f = *(const float4*)(Qg + (size_t)(m0 + row) * kHID + head * kHD + c4);
    bf16x4 hq;
    hq[0] = (bf16_t)(f.x * kQScale); hq[1] = (bf16_t)(f.y * kQScale);
    hq[2] = (bf16_t)(f.z * kQScale); hq[3] = (bf16_t)(f.w * kQScale);
    *(bf16x4*)(qs + row * kKP + c4) = hq;
  }
  __syncthreads();

  // O^T accumulators (32 regs, AGPR) + l partial
  f32x16 Oa0, Oa1;
  #pragma unroll
  for (int r = 0; r < 16; ++r) { Oa0[r] = 0.f; Oa1[r] = 0.f; }
  float lacc = 0.f;

  const int krow0 = lane >> 4;
  const int kc4   = (lane & 15) * 4;
  const float* kbase = Kg + head * kHD + kc4;
  const float* vbase = Vg + head * kHD + (size_t)(4 * h) * kHID + m31;

  float vv[32];   // V prefetch (kappa order) — the only backedge register block

  if (wave <= mtk) {
    const float* vt0 = vbase + (size_t)(wave * 32) * kHID;
    #pragma unroll
    for (int db = 0; db < 2; ++db)
      #pragma unroll
      for (int tp = 0; tp < 2; ++tp)
        #pragma unroll
        for (int j = 0; j < 8; ++j)
          vv[db * 16 + tp * 8 + j] =
              vt0[(size_t)(16 * tp + (j & 3) + 8 * (j >> 2)) * kHID + 32 * db];
  }

  for (int jt = wave; jt <= mtk; jt += 4) {
    const int kv0 = jt * 32;

    // a) consume vv into V A-frags BEFORE the refill overwrites it (WAR by order)
    bf16x8 va0, va1, va2, va3;
    #pragma unroll
    for (int j = 0; j < 8; ++j) {
      va0[j] = (bf16_t)vv[j];
      va1[j] = (bf16_t)vv[8 + j];
      va2[j] = (bf16_t)vv[16 + j];
      va3[j] = (bf16_t)vv[24 + j];
    }

    // b) prefetch next V tile (full iteration of cover)
    if (jt + 4 <= mtk) {
      const float* vt0 = vbase + (size_t)((jt + 4) * 32) * kHID;
      #pragma unroll
      for (int db = 0; db < 2; ++db)
        #pragma unroll
        for (int tp = 0; tp < 2; ++tp)
          #pragma unroll
          for (int j = 0; j < 8; ++j)
            vv[db * 16 + tp * 8 + j] =
                vt0[(size_t)(16 * tp + (j & 3) + 8 * (j >> 2)) * kHID + 32 * db];
    }

    // c) stage THIS tile's K in two 4-row batches (16 transient regs, no backedge)
    #pragma unroll
    for (int b = 0; b < 2; ++b) {
      float4 kr[4];
      #pragma unroll
      for (int i = 0; i < 4; ++i)
        kr[i] = *(const float4*)(kbase + (size_t)(kv0 + krow0 + 4 * (4 * b + i)) * kHID);
      #pragma unroll
      for (int i = 0; i < 4; ++i) {
        bf16x4 hk;
        hk[0] = (bf16_t)kr[i].x; hk[1] = (bf16_t)kr[i].y;
        hk[2] = (bf16_t)kr[i].z; hk[3] = (bf16_t)kr[i].w;
        *(bf16x4*)(ks + (krow0 + 4 * (4 * b + i)) * kKP + kc4) = hk;
      }
    }

    // d) S^T = K * Q^T (af and qf both from LDS; same-wave DS ordering)
    f32x16 cs;
    #pragma unroll
    for (int r = 0; r < 16; ++r) cs[r] = 0.f;
    #pragma unroll
    for (int t = 0; t < 4; ++t) {
      bf16x8 af = *(const bf16x8*)(ks + m31 * kKP + 16 * t + 8 * h);
      bf16x8 qf = *(const bf16x8*)(qs + m31 * kKP + 16 * t + 8 * h);
      cs = __builtin_amdgcn_mfma_f32_32x32x16_bf16(af, qf, cs, 0, 0, 0);
    }
    // C layout: key-row kr = (r&3)+8*(r>>2)+4h, q-col = m31

    // e) fixed-reference softmax (mask only on diagonal tile)
    float p[16];
    if (jt == mtk) {
      #pragma unroll
      for (int r = 0; r < 16; ++r) {
        const int kr = (r & 3) + 8 * (r >> 2) + 4 * h;
        const float e = __builtin_amdgcn_exp2f(cs[r]);
        p[r] = (kr <= m31) ? e : 0.f;
        lacc += p[r];
      }
    } else {
      #pragma unroll
      for (int r = 0; r < 16; ++r) { p[r] = __builtin_amdgcn_exp2f(cs[r]); lacc += p[r]; }
    }

    // f) P^T B-frags straight from C-regs; PV (kappa absorbed by V load order)
    bf16x8 pb0, pb1;
    #pragma unroll
    for (int j = 0; j < 8; ++j) { pb0[j] = (bf16_t)p[j]; pb1[j] = (bf16_t)p[8 + j]; }
    Oa0 = __builtin_amdgcn_mfma_f32_32x32x16_bf16(va0, pb0, Oa0, 0, 0, 0);
    Oa1 = __builtin_amdgcn_mfma_f32_32x32x16_bf16(va2, pb0, Oa1, 0, 0, 0);
    Oa0 = __builtin_amdgcn_mfma_f32_32x32x16_bf16(va1, pb1, Oa0, 0, 0, 0);
    Oa1 = __builtin_amdgcn_mfma_f32_32x32x16_bf16(va3, pb1, Oa1, 0, 0, 0);
  }

  // ---- epilogue: 4-way additive merge via LDS ----
  __syncthreads();
  float* fv   = (float*)smraw;
  float* Om   = fv + wave * 32 * kOmPitch;
  float* larr = fv + 4 * 32 * kOmPitch;

  #pragma unroll
  for (int md = 0; md < 2; ++md) {
    const f32x16& Oa = md ? Oa1 : Oa0;
    #pragma unroll
    for (int q = 0; q < 4; ++q) {
      f32x4 v;
      #pragma unroll
      for (int e = 0; e < 4; ++e) v[e] = Oa[4 * q + e];
      *(f32x4*)(Om + (size_t)m31 * kOmPitch + 32 * md + 8 * q + 4 * h) = v;
    }
  }
  larr[wave * 64 + lane] = lacc;
  __syncthreads();

  const int row = tid >> 3;
  const int c0  = (tid & 7) * 8;
  float l = 0.f;
  #pragma unroll
  for (int w = 0; w < 4; ++w)
    l += larr[w * 64 + row] + larr[w * 64 + 32 + row];
  const float inv = 1.f / l;

  f32x4 o0, o1;
  #pragma unroll
  for (int e = 0; e < 4; ++e) { o0[e] = 0.f; o1[e] = 0.f; }
  #pragma unroll
  for (int w = 0; w < 4; ++w) {
    const float* src = fv + w * 32 * kOmPitch + (size_t)row * kOmPitch + c0;
    f32x4 a = *(const f32x4*)(src);
    f32x4 b = *(const f32x4*)(src + 4);
    #pragma unroll
    for (int e = 0; e < 4; ++e) { o0[e] += a[e]; o1[e] += b[e]; }
  }
  #pragma unroll
  for (int e = 0; e < 4; ++e) { o0[e] *= inv; o1[e] *= inv; }

  float* dst = Og + (size_t)(m0 + row) * kHID + head * kHD + c0;
  *(f32x4*)(dst)     = o0;
  *(f32x4*)(dst + 4) = o1;
}

extern "C" void kernel_launch(void* const* d_in, const int* in_sizes, int n_in,
                              void* d_out, int out_size, void* d_ws, size_t ws_size,
                              hipStream_t stream) {
  (void)in_sizes; (void)n_in; (void)d_ws; (void)ws_size; (void)out_size;
  const float* Q = (const float*)d_in[0];
  const float* K = (const float*)d_in[1];
  const float* V = (const float*)d_in[2];
  float* O = (float*)d_out;
  dim3 grid(1024);   // 16 heads x 64 q-tiles (32 rows), 4-way balanced LPT
  dim3 block(256);   // 4 waves = 4 key-groups, barrier-free main loop
  hipLaunchKernelGGL(fattn_kernel, grid, block, 0, stream, Q, K, V, O);
}